// Round 16
// baseline (2058.096 us; speedup 1.0000x reference)
//
#include <hip/hip_runtime.h>
#include <hip/hip_bf16.h>

#define B_ 128
#define T_ 200
#define H_ 512
#define G_ 2048   // 4*H
#define E_ 300

typedef unsigned short u16;
typedef unsigned int u32;

using f32x4 = __attribute__((ext_vector_type(4))) float;
using s16x8 = __attribute__((ext_vector_type(8))) short;

__device__ __forceinline__ u16 f2bf(float f) {
  u32 u = __builtin_bit_cast(u32, f);
  u32 r = (u + 0x7fffu + ((u >> 16) & 1u)) >> 16;   // RNE
  return (u16)r;
}
__device__ __forceinline__ float bf2f(u16 s) {
  return __builtin_bit_cast(float, (u32)s << 16);
}

// ---- device-coherent (L1/L2-bypass) memory ops: sc0 sc1 (PROVEN r3-r14) ---
__device__ __forceinline__ s16x8 ld_h16_sc(const void* p) {
  s16x8 r;
  asm volatile("global_load_dwordx4 %0, %1, off sc0 sc1" : "=v"(r) : "v"(p));
  return r;
}
__device__ __forceinline__ void st_h_sc(void* p, u32 v) {   // low 16 bits
  asm volatile("global_store_short %0, %1, off sc0 sc1" :: "v"(p), "v"(v));
}
__device__ __forceinline__ u32 ld_flag_sc(const void* p) {
  u32 r;
  asm volatile("global_load_dword %0, %1, off sc0 sc1\n\ts_waitcnt vmcnt(0)"
               : "=v"(r) : "v"(p) : "memory");
  return r;
}
__device__ __forceinline__ void st_flag_sc(void* p, u32 v) {
  asm volatile("global_store_dword %0, %1, off sc0 sc1" :: "v"(p), "v"(v) : "memory");
}

// ---------------------------------------------------------------------------
// mask bits: mb[t*4 + w] = bit i <- (tok[(w*32+i)*T + t] != 0)
// ---------------------------------------------------------------------------
__global__ __launch_bounds__(64) void mask_k(
    const int* __restrict__ tok, u32* __restrict__ mb)
{
  const int idx = blockIdx.x * 64 + threadIdx.x;
  if (idx >= T_ * 4) return;
  const int t = idx >> 2, w = idx & 3;
  u32 bits = 0;
  for (int i = 0; i < 32; ++i)
    bits |= (tok[(w * 32 + i) * T_ + t] != 0 ? 1u : 0u) << i;
  mb[idx] = bits;
}

// ---------------------------------------------------------------------------
// Persistent LSTM, v16 = r10 h/flag protocol VERBATIM + self-produced xg.
// 256 WGs x 512 thr. WG = (grp 0..7 of 16 batch, jt 0..31 of 16 j).
// Waves: all 8 do Whh*h K-slice [wv*64,+64) (2 UC loads + 8 MFMA) as r10.
// ADDITIONALLY waves 4..7 (q = wv-4) produce this block's own xg slice for
// step t+1 during step t (while wave0 polls): A = emb[tok[b,t+1]] (cached
// loads, cvt to bf16), B = Wih quadrant-q frags held in VGPRs (loaded once),
// 10 MFMA (K=320 padded) -> LDS ring xr[(t+1)&1][q][lane] (f32x4).
// Wave0 epilogue reads xr (LDS) + bias (VGPR) instead of global xg.
// xr slot safety: read of slot s at epilogue(t-1) finishes before barrier
// C(t-1); the conflicting write of slot s happens at iter t AFTER C(t-1).
// h/flag protocol, barriers A/B/C, poll, drain: byte-identical to r10.
// ---------------------------------------------------------------------------
template<int TRACK_C>
__global__ __launch_bounds__(512, 2) void lstm_rec(
    const int* __restrict__ tok, const float* __restrict__ emb,
    const float* __restrict__ Wih, const float* __restrict__ bih,
    const float* __restrict__ bhh, const float* __restrict__ Whh,
    u16* __restrict__ hbuf, const float* __restrict__ c0in,
    float* __restrict__ cOut, float* __restrict__ mhOut,
    u32* __restrict__ flags, const u32* __restrict__ maskb)
{
  __shared__ f32x4 red[8][4][64];   // 32 KB: [kslice][q][lane]
  __shared__ f32x4 xr[2][4][64];    // 8 KB: xg ring [slot][q][lane]
  const int tid = threadIdx.x;
  const int wv = tid >> 6, ln = tid & 63, lr = ln & 15, lq = ln >> 4;
  const int grp = (int)blockIdx.x >> 5, jt = (int)blockIdx.x & 31;
  const int j0 = jt * 16, bg0 = grp * 16;
  u32* gflags = flags + grp * 512;          // 32 flags x 16 u32 pad

  // Whh B frags (all waves): Bf[q][ks] = Whh[q*512+j0+lr][wv*64+ks*32+lq*8..]
  s16x8 Bf[4][2];
#pragma unroll
  for (int q = 0; q < 4; ++q) {
    const float* wr = Whh + (size_t)(q * H_ + j0 + lr) * H_ + wv * 64 + lq * 8;
#pragma unroll
    for (int ks = 0; ks < 2; ++ks) {
      const float* wp = wr + ks * 32;
      s16x8 f;
#pragma unroll
      for (int i = 0; i < 8; ++i) f[i] = (short)f2bf(wp[i]);
      Bf[q][ks] = f;
    }
  }

  // waves 4..7: Wih frags for quadrant q: Wf[ks] = Wih[q*512+j0+lr][ks*32+lq*8..]
  const int qq = wv - 4;
  s16x8 Wf[10];
  if (wv >= 4) {
    const float* wr = Wih + (size_t)(qq * H_ + j0 + lr) * E_;
#pragma unroll
    for (int ks = 0; ks < 10; ++ks) {
      s16x8 f;
#pragma unroll
      for (int i = 0; i < 8; ++i) {
        const int k = ks * 32 + lq * 8 + i;
        f[i] = (short)((k < E_) ? f2bf(wr[k]) : (u16)0);
      }
      Wf[ks] = f;
    }
  }

  // wave0: cell state + bias[q] (bias depends on j only)
  float c[4], mb[4], bias[4];
#pragma unroll
  for (int r = 0; r < 4; ++r) {
    const int b = bg0 + lq * 4 + r;
    float cv = 0.f;
    if (!TRACK_C && wv == 0) cv = c0in[b * H_ + j0 + lr];
    c[r] = cv;
    mb[r] = TRACK_C ? cv : 0.f;
  }
  if (wv == 0) {
#pragma unroll
    for (int q = 0; q < 4; ++q) {
      const int g = q * H_ + j0 + lr;
      bias[q] = bih[g] + bhh[g];
    }
  }

  // prime: produce xg(0) into slot 0
  if (wv >= 4) {
    const int tk = tok[(bg0 + lr) * T_ + 0];
    const float* er = emb + (size_t)tk * E_;
    f32x4 xacc = {0.f, 0.f, 0.f, 0.f};
#pragma unroll
    for (int ks = 0; ks < 10; ++ks) {
      s16x8 af;
#pragma unroll
      for (int i = 0; i < 8; ++i) {
        const int k = ks * 32 + lq * 8 + i;
        af[i] = (short)((k < E_) ? f2bf(er[k]) : (u16)0);
      }
      xacc = __builtin_amdgcn_mfma_f32_16x16x32_bf16(af, Wf[ks], xacc, 0, 0, 0);
    }
    xr[0][qq][ln] = xacc;
  }
  __syncthreads();                           // prime barrier

  const u32* pp = gflags + (ln & 31) * 16;   // 32 flags, x2 lane duplication
  const int mword = grp >> 1, mshift = (grp & 1) * 16;

  for (int t = 0; t < T_; ++t) {
    const u16* hrd = hbuf + (t & 1) * (B_ * H_);
    u16* hwr = hbuf + ((t + 1) & 1) * (B_ * H_);

    u32 mku = 0;
    if (wv == 0) {
      mku = maskb[t * 4 + mword] >> mshift;
      // poll the group's 32 producer flags (tight loop) - r10 verbatim
      if (t > 0) {
        int guard = 0;
        for (;;) {
          u32 v = ld_flag_sc(pp);
          if (__all((int)(v >= (u32)t))) break;
          if (++guard > (1 << 22)) break;   // bail out instead of hanging
          __builtin_amdgcn_s_sleep(1);
        }
      }
    } else if (wv >= 4 && t + 1 < T_) {
      // produce xg(t+1) into slot (t+1)&1 (hidden under wave0's poll)
      const int tk = tok[(bg0 + lr) * T_ + (t + 1)];
      const float* er = emb + (size_t)tk * E_;
      f32x4 xacc = {0.f, 0.f, 0.f, 0.f};
#pragma unroll
      for (int ks = 0; ks < 10; ++ks) {
        s16x8 af;
#pragma unroll
        for (int i = 0; i < 8; ++i) {
          const int k = ks * 32 + lq * 8 + i;
          af[i] = (short)((k < E_) ? f2bf(er[k]) : (u16)0);
        }
        xacc = __builtin_amdgcn_mfma_f32_16x16x32_bf16(af, Wf[ks], xacc, 0, 0, 0);
      }
      xr[(t + 1) & 1][qq][ln] = xacc;
    }
    __syncthreads();                         // barrier A: h_t (+ xr write done)
    __builtin_amdgcn_sched_barrier(0);

    // h_t loads (coherent): rows = bg0+lr, k = wv*64 + ks*32 + lq*8
    s16x8 ha0, ha1;
    const u16* hb = hrd + (size_t)(bg0 + lr) * H_ + wv * 64 + lq * 8;
    ha0 = ld_h16_sc(hb);
    ha1 = ld_h16_sc(hb + 32);
    asm volatile("s_waitcnt vmcnt(0)" ::: "memory");
    __builtin_amdgcn_sched_barrier(0);

    f32x4 acc[4];
#pragma unroll
    for (int q = 0; q < 4; ++q) {
      acc[q] = __builtin_amdgcn_mfma_f32_16x16x32_bf16(ha0, Bf[q][0],
                   (f32x4){0.f, 0.f, 0.f, 0.f}, 0, 0, 0);
      acc[q] = __builtin_amdgcn_mfma_f32_16x16x32_bf16(ha1, Bf[q][1], acc[q], 0, 0, 0);
    }

    if (wv > 0) {
#pragma unroll
      for (int q = 0; q < 4; ++q) red[wv][q][ln] = acc[q];
    }
    __syncthreads();                         // barrier B: red ready
    if (wv == 0) {
#pragma unroll
      for (int kv = 1; kv < 8; ++kv)
#pragma unroll
        for (int q = 0; q < 4; ++q) acc[q] += red[kv][q][ln];
      // xg term from the LDS ring (slot t&1)
      f32x4 xv[4];
#pragma unroll
      for (int q = 0; q < 4; ++q) xv[q] = xr[t & 1][q][ln];
      const bool last = (t == T_ - 1);
#pragma unroll
      for (int r = 0; r < 4; ++r) {
        const int b = bg0 + lq * 4 + r;
        const float gi = acc[0][r] + xv[0][r] + bias[0];
        const float gf = acc[1][r] + xv[1][r] + bias[1];
        const float gG = acc[2][r] + xv[2][r] + bias[2];
        const float go = acc[3][r] + xv[3][r] + bias[3];
        const float si = 1.f / (1.f + __expf(-gi));
        const float sf = 1.f / (1.f + __expf(-gf));
        const float so = 1.f / (1.f + __expf(-go));
        const float tg = 2.f / (1.f + __expf(-2.f * gG)) - 1.f;
        const float cn = sf * c[r] + si * tg;
        const float tc = 2.f / (1.f + __expf(-2.f * cn)) - 1.f;
        const float hn = so * tc;
        c[r] = cn;
        if ((mku >> (lq * 4 + r)) & 1u) mb[r] = TRACK_C ? cn : hn;
        if (!last) st_h_sc(hwr + (size_t)b * H_ + j0 + lr, (u32)f2bf(hn));
      }
      if (t + 1 < T_) {
        asm volatile("s_waitcnt vmcnt(0)" ::: "memory");   // drain h stores
        if (ln == 0) st_flag_sc(gflags + jt * 16, (u32)(t + 1));
      }
    }
    __syncthreads();                         // barrier C (r10 verbatim;
                                             // also orders xr slot reuse)
  }

  if (wv == 0) {
#pragma unroll
    for (int r = 0; r < 4; ++r) {
      const int b = bg0 + lq * 4 + r;
      if (TRACK_C) cOut[b * H_ + j0 + lr] = mb[r];
      else         mhOut[b * H_ + j0 + lr] = mb[r];
    }
  }
}

// ---------------------------------------------------------------------------
// head: logits = [mh, sim] @ fcW^T + fcb ; log_softmax
// ---------------------------------------------------------------------------
__global__ __launch_bounds__(128) void final_k(
    const float* __restrict__ mh, const float* __restrict__ sim,
    const float* __restrict__ fcW, const float* __restrict__ fcb,
    float* __restrict__ out)
{
  const int b = threadIdx.x;
  float l[3];
#pragma unroll
  for (int cc = 0; cc < 3; ++cc) {
    const float* wr = fcW + cc * (H_ + 1);
    float s = fcb[cc] + sim[b] * wr[H_];
    for (int j = 0; j < H_; ++j) s += mh[b * H_ + j] * wr[j];
    l[cc] = s;
  }
  const float m = fmaxf(l[0], fmaxf(l[1], l[2]));
  const float lse = m + logf(__expf(l[0] - m) + __expf(l[1] - m) + __expf(l[2] - m));
  out[b * 3 + 0] = l[0] - lse;
  out[b * 3 + 1] = l[1] - lse;
  out[b * 3 + 2] = l[2] - lse;
}

extern "C" void kernel_launch(void* const* d_in, const int* in_sizes, int n_in,
                              void* d_out, int out_size, void* d_ws, size_t ws_size,
                              hipStream_t stream) {
  const int*   prem = (const int*)d_in[0];
  const int*   hypo = (const int*)d_in[1];
  const float* sim  = (const float*)d_in[2];
  const float* emb  = (const float*)d_in[3];
  const float* WihP = (const float*)d_in[4];
  const float* WhhP = (const float*)d_in[5];
  const float* bihP = (const float*)d_in[6];
  const float* bhhP = (const float*)d_in[7];
  const float* WihH = (const float*)d_in[8];
  const float* WhhH = (const float*)d_in[9];
  const float* bihH = (const float*)d_in[10];
  const float* bhhH = (const float*)d_in[11];
  const float* fcW  = (const float*)d_in[12];
  const float* fcb  = (const float*)d_in[13];
  float* out = (float*)d_out;

  char* ws = (char*)d_ws;
  const size_t HB_OFF = 0;                                // 2 x 128 x 512 bf16
  const size_t CL_OFF = HB_OFF + (size_t)2 * B_ * H_ * 2;
  const size_t MH_OFF = CL_OFF + (size_t)B_ * H_ * 4;
  const size_t FL_OFF = MH_OFF + (size_t)B_ * H_ * 4;     // 2 x 16 KB flags
  const size_t MK_OFF = FL_OFF + 32768;                   // 2 x 4 KB maskbits
  const size_t NEED   = MK_OFF + 8192;                    // ~1.1 MB
  if (ws_size < NEED) return;  // visible failure instead of OOB corruption

  u16*   hbuf  = (u16*)(ws + HB_OFF);
  float* cLast = (float*)(ws + CL_OFF);
  float* mh    = (float*)(ws + MH_OFF);
  u32*   flagsP = (u32*)(ws + FL_OFF);        // 8 grp x 32 x 64B
  u32*   flagsH = flagsP + 4096;
  u32*   maskbP = (u32*)(ws + MK_OFF);        // 200 x 4 u32
  u32*   maskbH = maskbP + 1024;

  hipMemsetAsync(ws + FL_OFF, 0, 32768, stream);          // both flag regions

  mask_k<<<13, 64, 0, stream>>>(prem, maskbP);
  mask_k<<<13, 64, 0, stream>>>(hypo, maskbH);
  hipMemsetAsync(hbuf, 0, (size_t)B_ * H_ * 2, stream);   // h0 = 0 (buffer 0)
  lstm_rec<1><<<256, 512, 0, stream>>>(prem, emb, WihP, bihP, bhhP, WhhP,
                                       hbuf, nullptr, cLast, nullptr,
                                       flagsP, maskbP);
  hipMemsetAsync(hbuf, 0, (size_t)B_ * H_ * 2, stream);   // h0 = 0 (buffer 0)
  lstm_rec<0><<<256, 512, 0, stream>>>(hypo, emb, WihH, bihH, bhhH, WhhH,
                                       hbuf, cLast, nullptr, mh,
                                       flagsH, maskbH);
  final_k<<<1, 128, 0, stream>>>(mh, sim, fcW, fcb, out);
}